// Round 1
// baseline (1766.712 us; speedup 1.0000x reference)
//
#include <hip/hip_runtime.h>

// ---------------------------------------------------------------------------
// GATv2 3-layer GNN encoder. N=50000 nodes, E=800000 edges, dims 128.
// Phases: CSR build (once) -> per layer: [gemm xl, gemm xr, edge scores,
// node softmax+aggregate+LN+ReLU fused].
// ---------------------------------------------------------------------------

__global__ __launch_bounds__(256) void hist_kernel(const int* __restrict__ dst,
                                                   int* __restrict__ deg, int nE) {
  int i = blockIdx.x * 256 + threadIdx.x;
  if (i < nE) atomicAdd(&deg[dst[i]], 1);
}

__global__ __launch_bounds__(1024) void scan_kernel(const int* __restrict__ deg,
                                                    int* __restrict__ rowptr, int n) {
  __shared__ int sdata[1024];
  int tid = threadIdx.x;
  if (tid == 0) rowptr[0] = 0;
  int carry = 0;
  for (int base = 0; base < n; base += 1024) {
    int i = base + tid;
    int v = (i < n) ? deg[i] : 0;
    sdata[tid] = v;
    __syncthreads();
    for (int ofs = 1; ofs < 1024; ofs <<= 1) {
      int t = (tid >= ofs) ? sdata[tid - ofs] : 0;
      __syncthreads();
      sdata[tid] += t;
      __syncthreads();
    }
    int inc = sdata[tid];
    int tot = sdata[1023];
    if (i < n) rowptr[i + 1] = carry + inc;
    carry += tot;
    __syncthreads();
  }
}

__global__ __launch_bounds__(256) void scatter_kernel(const int* __restrict__ dst,
                                                      const int* __restrict__ rowptr,
                                                      int* __restrict__ cnt,
                                                      int* __restrict__ eperm, int nE) {
  int i = blockIdx.x * 256 + threadIdx.x;
  if (i < nE) {
    int d = dst[i];
    int p = atomicAdd(&cnt[d], 1);
    eperm[rowptr[d] + p] = i;
  }
}

// Y[r][c] = sum_k X[r][k]*W[k][c] + bias[c].  X: nrows x 128, W: 128 x 128.
// Block: 256 threads -> 64 rows x 128 cols.  Thread t: col = t&127, owns 32 rows.
__global__ __launch_bounds__(256) void node_gemm128(const float* __restrict__ X,
                                                    const float* __restrict__ W,
                                                    const float* __restrict__ bias,
                                                    float* __restrict__ Y, int nrows) {
  __shared__ float Xs[64][36];   // pad 36: float4-aligned + conflict-free writes
  __shared__ float Ws[32][128];
  int tid = threadIdx.x;
  int r0 = blockIdx.x * 64;
  int col = tid & 127;
  int rh = tid >> 7;  // 0 or 1: which 32-row half
  float acc[32];
#pragma unroll
  for (int i = 0; i < 32; ++i) acc[i] = 0.f;

  for (int k0 = 0; k0 < 128; k0 += 32) {
    __syncthreads();
#pragma unroll
    for (int j = tid; j < 512; j += 256) {   // 64x32 X tile as 512 float4
      int r = j >> 3, kk = (j & 7) << 2;
      float4 v = make_float4(0.f, 0.f, 0.f, 0.f);
      if (r0 + r < nrows) v = *(const float4*)&X[(size_t)(r0 + r) * 128 + k0 + kk];
      *(float4*)&Xs[r][kk] = v;
    }
#pragma unroll
    for (int j = tid; j < 1024; j += 256) {  // 32x128 W tile as 1024 float4
      int k = j >> 5, nn = (j & 31) << 2;
      float4 v = *(const float4*)&W[(size_t)(k0 + k) * 128 + nn];
      *(float4*)&Ws[k][nn] = v;
    }
    __syncthreads();
#pragma unroll
    for (int k4 = 0; k4 < 32; k4 += 4) {
      float w0 = Ws[k4][col], w1 = Ws[k4 + 1][col];
      float w2 = Ws[k4 + 2][col], w3 = Ws[k4 + 3][col];
#pragma unroll
      for (int r = 0; r < 32; ++r) {
        float4 xv = *(const float4*)&Xs[rh * 32 + r][k4];  // wave-uniform: LDS broadcast
        acc[r] += xv.x * w0 + xv.y * w1 + xv.z * w2 + xv.w * w3;
      }
    }
  }
  float b = bias[col];
#pragma unroll
  for (int r = 0; r < 32; ++r) {
    int row = r0 + rh * 32 + r;
    if (row < nrows) Y[(size_t)row * 128 + col] = acc[r] + b;
  }
}

// s[e,h] = sum_c lrelu(xl[src[e]][c] + xr[dst[e]][c] + (ea[e]@We)[c]) * att[c]
// 128 threads = feature dims. We column in 32 regs/thread. 128 edges/block.
template <int H>
__global__ __launch_bounds__(128) void edge_scores(const float* __restrict__ xl,
                                                   const float* __restrict__ xr,
                                                   const float* __restrict__ ea,
                                                   const float* __restrict__ We,
                                                   const float* __restrict__ att,
                                                   const int* __restrict__ src,
                                                   const int* __restrict__ dst,
                                                   float* __restrict__ sout, int nE) {
  __shared__ float eas[32][36];
  __shared__ float sred[32][4];
  __shared__ int sd[32][2];
  int tid = threadIdx.x;  // 0..127 = output feature c
  float Wc[32];
#pragma unroll
  for (int k = 0; k < 32; ++k) Wc[k] = We[k * 128 + tid];
  float attc = att[tid];
  int base0 = blockIdx.x * 128;

  for (int b = 0; b < 4; ++b) {
    int ebase = base0 + b * 32;
    __syncthreads();  // protect eas/sred from previous batch
#pragma unroll
    for (int j = tid; j < 256; j += 128) {  // 32 edges x 32 dims = 256 float4
      int e = j >> 3, kk = (j & 7) << 2;
      float4 v = make_float4(0.f, 0.f, 0.f, 0.f);
      if (ebase + e < nE) v = *(const float4*)&ea[(size_t)(ebase + e) * 32 + kk];
      *(float4*)&eas[e][kk] = v;
    }
    if (tid < 32 && ebase + tid < nE) {
      sd[tid][0] = src[ebase + tid];
      sd[tid][1] = dst[ebase + tid];
    }
    __syncthreads();
    int elim = min(32, nE - ebase);
    for (int i = 0; i < elim; ++i) {
      int se = sd[i][0], de = sd[i][1];
      float m = xl[(size_t)se * 128 + tid] + xr[(size_t)de * 128 + tid];
#pragma unroll
      for (int k = 0; k < 32; k += 4) {
        float4 e4 = *(const float4*)&eas[i][k];  // wave-uniform: LDS broadcast
        m += e4.x * Wc[k] + e4.y * Wc[k + 1] + e4.z * Wc[k + 2] + e4.w * Wc[k + 3];
      }
      m = (m > 0.f) ? m : 0.2f * m;  // LeakyReLU(0.2)
      float p = m * attc;
#pragma unroll
      for (int o = 16; o >= 1; o >>= 1) p += __shfl_xor(p, o, 32);  // reduce 32-lane group
      if ((tid & 31) == 0) sred[i][tid >> 5] = p;
    }
    __syncthreads();
    if (H == 4) {
      int i = tid >> 2, h = tid & 3;  // per-32-lane group == head
      if (ebase + i < nE) sout[(size_t)(ebase + i) * 4 + h] = sred[i][h];
    } else {
      if (tid < 32 && ebase + tid < nE)
        sout[ebase + tid] = sred[tid][0] + sred[tid][1] + sred[tid][2] + sred[tid][3];
    }
  }
}

// Per node: softmax over in-edges (CSR), aggregate alpha*xl[src], +bias, LN, ReLU.
// One 64-lane wave per node; lane owns feature dims {lane, lane+64}.
template <int H>
__global__ __launch_bounds__(256) void node_aggregate(const float* __restrict__ xl,
                                                      const float* __restrict__ s,
                                                      const int* __restrict__ rowptr,
                                                      const int* __restrict__ eperm,
                                                      const int* __restrict__ src,
                                                      const float* __restrict__ bias,
                                                      const float* __restrict__ gam,
                                                      const float* __restrict__ bet,
                                                      float* __restrict__ out, int nN) {
  int wid = threadIdx.x >> 6, lane = threadIdx.x & 63;
  int n = blockIdx.x * 4 + wid;
  if (n >= nN) return;
  int rb = rowptr[n], re = rowptr[n + 1];

  float mx[H];
#pragma unroll
  for (int h = 0; h < H; ++h) mx[h] = -1e30f;
  for (int j = rb + lane; j < re; j += 64) {
    int e = eperm[j];
#pragma unroll
    for (int h = 0; h < H; ++h) mx[h] = fmaxf(mx[h], s[(size_t)e * H + h]);
  }
#pragma unroll
  for (int o = 32; o >= 1; o >>= 1) {
#pragma unroll
    for (int h = 0; h < H; ++h) mx[h] = fmaxf(mx[h], __shfl_xor(mx[h], o));
  }
  float den[H];
#pragma unroll
  for (int h = 0; h < H; ++h) den[h] = 0.f;
  for (int j = rb + lane; j < re; j += 64) {
    int e = eperm[j];
#pragma unroll
    for (int h = 0; h < H; ++h) den[h] += __expf(s[(size_t)e * H + h] - mx[h]);
  }
#pragma unroll
  for (int o = 32; o >= 1; o >>= 1) {
#pragma unroll
    for (int h = 0; h < H; ++h) den[h] += __shfl_xor(den[h], o);
  }

  // per-lane head selection without runtime-indexed register arrays (rule #20)
  float mxq0, mxq1, rdq0, rdq1;
  int hq0, hq1;
  if (H == 4) {
    int gsel = lane >> 5;  // q=0: heads 0/1, q=1: heads 2/3
    mxq0 = gsel ? mx[1] : mx[0];
    mxq1 = gsel ? mx[3] : mx[2];
    rdq0 = 1.f / (gsel ? den[1] : den[0]);
    rdq1 = 1.f / (gsel ? den[3] : den[2]);
    hq0 = gsel;
    hq1 = 2 + gsel;
  } else {
    mxq0 = mxq1 = mx[0];
    rdq0 = rdq1 = 1.f / den[0];
    hq0 = hq1 = 0;
  }

  float acc0 = 0.f, acc1 = 0.f;
  for (int j = rb; j < re; ++j) {
    int e = eperm[j];  // wave-uniform
    int sr = src[e];
    float a0 = __expf(s[(size_t)e * H + hq0] - mxq0) * rdq0;
    float a1 = __expf(s[(size_t)e * H + hq1] - mxq1) * rdq1;
    const float* xrow = xl + (size_t)sr * 128;
    acc0 += a0 * xrow[lane];        // coalesced 256B
    acc1 += a1 * xrow[lane + 64];   // coalesced 256B
  }

  float y0 = acc0 + bias[lane], y1 = acc1 + bias[lane + 64];
  float sm = y0 + y1;
#pragma unroll
  for (int o = 32; o >= 1; o >>= 1) sm += __shfl_xor(sm, o);
  float mu = sm * (1.f / 128.f);
  float d0 = y0 - mu, d1 = y1 - mu;
  float vs = d0 * d0 + d1 * d1;
#pragma unroll
  for (int o = 32; o >= 1; o >>= 1) vs += __shfl_xor(vs, o);
  float rstd = rsqrtf(vs * (1.f / 128.f) + 1e-5f);
  float o0 = d0 * rstd * gam[lane] + bet[lane];
  float o1 = d1 * rstd * gam[lane + 64] + bet[lane + 64];
  out[(size_t)n * 128 + lane] = fmaxf(o0, 0.f);
  out[(size_t)n * 128 + lane + 64] = fmaxf(o1, 0.f);
}

extern "C" void kernel_launch(void* const* d_in, const int* in_sizes, int n_in,
                              void* d_out, int out_size, void* d_ws, size_t ws_size,
                              hipStream_t stream) {
  const float* x = (const float*)d_in[0];
  const float* ea = (const float*)d_in[1];
  const int* src = (const int*)d_in[2];
  const int* dst = (const int*)d_in[3];
  const int N = in_sizes[0] / 128;
  const int E = in_sizes[2];

  char* w = (char*)d_ws;
  auto alloc = [&](size_t bytes) {
    char* p = w;
    w += (bytes + 255) & ~(size_t)255;
    return p;
  };
  float* xl = (float*)alloc((size_t)N * 128 * 4);
  float* xr = (float*)alloc((size_t)N * 128 * 4);
  float* hA = (float*)alloc((size_t)N * 128 * 4);
  float* hB = (float*)alloc((size_t)N * 128 * 4);
  float* sbuf = (float*)alloc((size_t)E * 4 * 4);
  int* eperm = (int*)alloc((size_t)E * 4);
  int* rowptr = (int*)alloc((size_t)(N + 1) * 4);
  int* deg = (int*)alloc((size_t)N * 4);
  int* cnt = (int*)alloc((size_t)N * 4);

  // CSR by dst (src/dst constant across layers)
  hipMemsetAsync(deg, 0, (size_t)N * 4, stream);
  hipMemsetAsync(cnt, 0, (size_t)N * 4, stream);
  hist_kernel<<<(E + 255) / 256, 256, 0, stream>>>(dst, deg, E);
  scan_kernel<<<1, 1024, 0, stream>>>(deg, rowptr, N);
  scatter_kernel<<<(E + 255) / 256, 256, 0, stream>>>(dst, rowptr, cnt, eperm, E);

  for (int l = 0; l < 3; ++l) {
    int bi = 4 + 9 * l;
    const float* Wl = (const float*)d_in[bi + 0];
    const float* bl = (const float*)d_in[bi + 1];
    const float* Wr = (const float*)d_in[bi + 2];
    const float* br = (const float*)d_in[bi + 3];
    const float* We = (const float*)d_in[bi + 4];
    const float* att = (const float*)d_in[bi + 5];
    const float* bo = (const float*)d_in[bi + 6];
    const float* gg = (const float*)d_in[bi + 7];
    const float* be = (const float*)d_in[bi + 8];
    const float* Xin = (l == 0) ? x : ((l == 1) ? hA : hB);
    float* Xout = (l == 2) ? (float*)d_out : ((l == 0) ? hA : hB);

    int gemmGrid = (N + 63) / 64;
    node_gemm128<<<gemmGrid, 256, 0, stream>>>(Xin, Wl, bl, xl, N);
    node_gemm128<<<gemmGrid, 256, 0, stream>>>(Xin, Wr, br, xr, N);
    int eGrid = (E + 127) / 128;
    if (l < 2) {
      edge_scores<4><<<eGrid, 128, 0, stream>>>(xl, xr, ea, We, att, src, dst, sbuf, E);
      node_aggregate<4><<<(N + 3) / 4, 256, 0, stream>>>(xl, sbuf, rowptr, eperm, src,
                                                         bo, gg, be, Xout, N);
    } else {
      edge_scores<1><<<eGrid, 128, 0, stream>>>(xl, xr, ea, We, att, src, dst, sbuf, E);
      node_aggregate<1><<<(N + 3) / 4, 256, 0, stream>>>(xl, sbuf, rowptr, eperm, src,
                                                         bo, gg, be, Xout, N);
    }
  }
}

// Round 2
// 1645.409 us; speedup vs baseline: 1.0737x; 1.0737x over previous
//
#include <hip/hip_runtime.h>

// ---------------------------------------------------------------------------
// GATv2 3-layer GNN encoder. N=50000 nodes, E=800000 edges, dims 128.
// Phases: CSR build (once) -> per layer: [gemm xl, gemm xr, edge scores,
// node softmax+aggregate+LN+ReLU fused].
// ---------------------------------------------------------------------------

__global__ __launch_bounds__(256) void hist_kernel(const int* __restrict__ dst,
                                                   int* __restrict__ deg, int nE) {
  int i = blockIdx.x * 256 + threadIdx.x;
  if (i < nE) atomicAdd(&deg[dst[i]], 1);
}

__global__ __launch_bounds__(1024) void scan_kernel(const int* __restrict__ deg,
                                                    int* __restrict__ rowptr, int n) {
  __shared__ int sdata[1024];
  int tid = threadIdx.x;
  if (tid == 0) rowptr[0] = 0;
  int carry = 0;
  for (int base = 0; base < n; base += 1024) {
    int i = base + tid;
    int v = (i < n) ? deg[i] : 0;
    sdata[tid] = v;
    __syncthreads();
    for (int ofs = 1; ofs < 1024; ofs <<= 1) {
      int t = (tid >= ofs) ? sdata[tid - ofs] : 0;
      __syncthreads();
      sdata[tid] += t;
      __syncthreads();
    }
    int inc = sdata[tid];
    int tot = sdata[1023];
    if (i < n) rowptr[i + 1] = carry + inc;
    carry += tot;
    __syncthreads();
  }
}

__global__ __launch_bounds__(256) void scatter_kernel(const int* __restrict__ dst,
                                                      const int* __restrict__ rowptr,
                                                      int* __restrict__ cnt,
                                                      int* __restrict__ eperm, int nE) {
  int i = blockIdx.x * 256 + threadIdx.x;
  if (i < nE) {
    int d = dst[i];
    int p = atomicAdd(&cnt[d], 1);
    eperm[rowptr[d] + p] = i;
  }
}

// Y[r][c] = sum_k X[r][k]*W[k][c] + bias[c].  X: nrows x 128, W: 128 x 128.
// Block: 256 threads -> 64 rows x 128 cols.  Thread t: col = t&127, owns 32 rows.
__global__ __launch_bounds__(256) void node_gemm128(const float* __restrict__ X,
                                                    const float* __restrict__ W,
                                                    const float* __restrict__ bias,
                                                    float* __restrict__ Y, int nrows) {
  __shared__ float Xs[64][36];   // pad 36: float4-aligned + conflict-free writes
  __shared__ float Ws[32][128];
  int tid = threadIdx.x;
  int r0 = blockIdx.x * 64;
  int col = tid & 127;
  int rh = tid >> 7;  // 0 or 1: which 32-row half
  float acc[32];
#pragma unroll
  for (int i = 0; i < 32; ++i) acc[i] = 0.f;

  for (int k0 = 0; k0 < 128; k0 += 32) {
    __syncthreads();
#pragma unroll
    for (int j = tid; j < 512; j += 256) {   // 64x32 X tile as 512 float4
      int r = j >> 3, kk = (j & 7) << 2;
      float4 v = make_float4(0.f, 0.f, 0.f, 0.f);
      if (r0 + r < nrows) v = *(const float4*)&X[(size_t)(r0 + r) * 128 + k0 + kk];
      *(float4*)&Xs[r][kk] = v;
    }
#pragma unroll
    for (int j = tid; j < 1024; j += 256) {  // 32x128 W tile as 1024 float4
      int k = j >> 5, nn = (j & 31) << 2;
      float4 v = *(const float4*)&W[(size_t)(k0 + k) * 128 + nn];
      *(float4*)&Ws[k][nn] = v;
    }
    __syncthreads();
#pragma unroll
    for (int k4 = 0; k4 < 32; k4 += 4) {
      float w0 = Ws[k4][col], w1 = Ws[k4 + 1][col];
      float w2 = Ws[k4 + 2][col], w3 = Ws[k4 + 3][col];
#pragma unroll
      for (int r = 0; r < 32; ++r) {
        float4 xv = *(const float4*)&Xs[rh * 32 + r][k4];  // wave-uniform: LDS broadcast
        acc[r] += xv.x * w0 + xv.y * w1 + xv.z * w2 + xv.w * w3;
      }
    }
  }
  float b = bias[col];
#pragma unroll
  for (int r = 0; r < 32; ++r) {
    int row = r0 + rh * 32 + r;
    if (row < nrows) Y[(size_t)row * 128 + col] = acc[r] + b;
  }
}

// s[e,h] = sum_c lrelu(xl[src[e]][c] + xr[dst[e]][c] + (ea[e]@We)[c]) * att[c]
// One independent wave per EPW edges. Lane owns dims {lane, lane+64}; We columns
// held in 64 registers. ea/src/dst are wave-uniform -> readfirstlane -> s_load.
// 4 edges in flight for ILP. No LDS, no barriers.
#define EPW 64
template <int H>
__global__ __launch_bounds__(256) void edge_scores(const float* __restrict__ xl,
                                                   const float* __restrict__ xr,
                                                   const float* __restrict__ ea,
                                                   const float* __restrict__ We,
                                                   const float* __restrict__ att,
                                                   const int* __restrict__ src,
                                                   const int* __restrict__ dst,
                                                   float* __restrict__ sout, int nE) {
  const int lane = threadIdx.x & 63;
  const int gwave = (blockIdx.x * 256 + threadIdx.x) >> 6;
  const int e0 = gwave * EPW;
  if (e0 >= nE) return;

  float WcL[32], WcH[32];
#pragma unroll
  for (int k = 0; k < 32; ++k) {
    WcL[k] = We[k * 128 + lane];
    WcH[k] = We[k * 128 + lane + 64];
  }
  const float aL = att[lane], aH = att[lane + 64];  // att flat [h*32+c] == att[c]

  for (int i0 = 0; i0 < EPW; i0 += 4) {
    float mL[4], mH[4];
#pragma unroll
    for (int j = 0; j < 4; ++j) {
      int e = e0 + i0 + j;
      if (e >= nE) e = nE - 1;  // clamp; store predicated below
      int eu = __builtin_amdgcn_readfirstlane(e);
      int se = __builtin_amdgcn_readfirstlane(src[eu]);
      int de = __builtin_amdgcn_readfirstlane(dst[eu]);
      const float* xlr = xl + (size_t)se * 128;
      const float* xrr = xr + (size_t)de * 128;
      float accL = xlr[lane] + xrr[lane];
      float accH = xlr[lane + 64] + xrr[lane + 64];
      const float* er = ea + (size_t)eu * 32;
#pragma unroll
      for (int k = 0; k < 32; k += 4) {
        float4 a4 = *(const float4*)(er + k);  // uniform addr -> s_load_dwordx4
        accL += a4.x * WcL[k] + a4.y * WcL[k + 1] + a4.z * WcL[k + 2] + a4.w * WcL[k + 3];
        accH += a4.x * WcH[k] + a4.y * WcH[k + 1] + a4.z * WcH[k + 2] + a4.w * WcH[k + 3];
      }
      mL[j] = accL;
      mH[j] = accH;
    }
#pragma unroll
    for (int j = 0; j < 4; ++j) {
      // LeakyReLU(0.2): max(x, 0.2x)
      float pL = fmaxf(mL[j], 0.2f * mL[j]) * aL;
      float pH = fmaxf(mH[j], 0.2f * mH[j]) * aH;
      int e = e0 + i0 + j;
      if (H == 4) {
#pragma unroll
        for (int o = 16; o >= 1; o >>= 1) {
          pL += __shfl_xor(pL, o);
          pH += __shfl_xor(pH, o);
        }
        // lane 0: heads 0 (pL) / 2 (pH); lane 32: heads 1 (pL) / 3 (pH)
        if (e < nE && (lane & 31) == 0) {
          int h = lane >> 5;
          sout[(size_t)e * 4 + h] = pL;
          sout[(size_t)e * 4 + h + 2] = pH;
        }
      } else {
        float p = pL + pH;
#pragma unroll
        for (int o = 32; o >= 1; o >>= 1) p += __shfl_xor(p, o);
        if (e < nE && lane == 0) sout[e] = p;
      }
    }
  }
}

// Per node: softmax over in-edges (CSR), aggregate alpha*xl[src], +bias, LN, ReLU.
// One 64-lane wave per node; lane owns feature dims {lane, lane+64}.
template <int H>
__global__ __launch_bounds__(256) void node_aggregate(const float* __restrict__ xl,
                                                      const float* __restrict__ s,
                                                      const int* __restrict__ rowptr,
                                                      const int* __restrict__ eperm,
                                                      const int* __restrict__ src,
                                                      const float* __restrict__ bias,
                                                      const float* __restrict__ gam,
                                                      const float* __restrict__ bet,
                                                      float* __restrict__ out, int nN) {
  int wid = threadIdx.x >> 6, lane = threadIdx.x & 63;
  int n = blockIdx.x * 4 + wid;
  if (n >= nN) return;
  int rb = rowptr[n], re = rowptr[n + 1];

  float mx[H];
#pragma unroll
  for (int h = 0; h < H; ++h) mx[h] = -1e30f;
  for (int j = rb + lane; j < re; j += 64) {
    int e = eperm[j];
#pragma unroll
    for (int h = 0; h < H; ++h) mx[h] = fmaxf(mx[h], s[(size_t)e * H + h]);
  }
#pragma unroll
  for (int o = 32; o >= 1; o >>= 1) {
#pragma unroll
    for (int h = 0; h < H; ++h) mx[h] = fmaxf(mx[h], __shfl_xor(mx[h], o));
  }
  float den[H];
#pragma unroll
  for (int h = 0; h < H; ++h) den[h] = 0.f;
  for (int j = rb + lane; j < re; j += 64) {
    int e = eperm[j];
#pragma unroll
    for (int h = 0; h < H; ++h) den[h] += __expf(s[(size_t)e * H + h] - mx[h]);
  }
#pragma unroll
  for (int o = 32; o >= 1; o >>= 1) {
#pragma unroll
    for (int h = 0; h < H; ++h) den[h] += __shfl_xor(den[h], o);
  }

  // per-lane head selection without runtime-indexed register arrays (rule #20)
  float mxq0, mxq1, rdq0, rdq1;
  int hq0, hq1;
  if (H == 4) {
    int gsel = lane >> 5;  // q=0: heads 0/1, q=1: heads 2/3
    mxq0 = gsel ? mx[1] : mx[0];
    mxq1 = gsel ? mx[3] : mx[2];
    rdq0 = 1.f / (gsel ? den[1] : den[0]);
    rdq1 = 1.f / (gsel ? den[3] : den[2]);
    hq0 = gsel;
    hq1 = 2 + gsel;
  } else {
    mxq0 = mxq1 = mx[0];
    rdq0 = rdq1 = 1.f / den[0];
    hq0 = hq1 = 0;
  }

  float acc0 = 0.f, acc1 = 0.f;
  for (int j = rb; j < re; ++j) {
    int e = eperm[j];  // wave-uniform
    int sr = src[e];
    float a0 = __expf(s[(size_t)e * H + hq0] - mxq0) * rdq0;
    float a1 = __expf(s[(size_t)e * H + hq1] - mxq1) * rdq1;
    const float* xrow = xl + (size_t)sr * 128;
    acc0 += a0 * xrow[lane];        // coalesced 256B
    acc1 += a1 * xrow[lane + 64];   // coalesced 256B
  }

  float y0 = acc0 + bias[lane], y1 = acc1 + bias[lane + 64];
  float sm = y0 + y1;
#pragma unroll
  for (int o = 32; o >= 1; o >>= 1) sm += __shfl_xor(sm, o);
  float mu = sm * (1.f / 128.f);
  float d0 = y0 - mu, d1 = y1 - mu;
  float vs = d0 * d0 + d1 * d1;
#pragma unroll
  for (int o = 32; o >= 1; o >>= 1) vs += __shfl_xor(vs, o);
  float rstd = rsqrtf(vs * (1.f / 128.f) + 1e-5f);
  float o0 = d0 * rstd * gam[lane] + bet[lane];
  float o1 = d1 * rstd * gam[lane + 64] + bet[lane + 64];
  out[(size_t)n * 128 + lane] = fmaxf(o0, 0.f);
  out[(size_t)n * 128 + lane + 64] = fmaxf(o1, 0.f);
}

extern "C" void kernel_launch(void* const* d_in, const int* in_sizes, int n_in,
                              void* d_out, int out_size, void* d_ws, size_t ws_size,
                              hipStream_t stream) {
  const float* x = (const float*)d_in[0];
  const float* ea = (const float*)d_in[1];
  const int* src = (const int*)d_in[2];
  const int* dst = (const int*)d_in[3];
  const int N = in_sizes[0] / 128;
  const int E = in_sizes[2];

  char* w = (char*)d_ws;
  auto alloc = [&](size_t bytes) {
    char* p = w;
    w += (bytes + 255) & ~(size_t)255;
    return p;
  };
  float* xl = (float*)alloc((size_t)N * 128 * 4);
  float* xr = (float*)alloc((size_t)N * 128 * 4);
  float* hA = (float*)alloc((size_t)N * 128 * 4);
  float* hB = (float*)alloc((size_t)N * 128 * 4);
  float* sbuf = (float*)alloc((size_t)E * 4 * 4);
  int* eperm = (int*)alloc((size_t)E * 4);
  int* rowptr = (int*)alloc((size_t)(N + 1) * 4);
  int* deg = (int*)alloc((size_t)N * 4);
  int* cnt = (int*)alloc((size_t)N * 4);

  // CSR by dst (src/dst constant across layers)
  hipMemsetAsync(deg, 0, (size_t)N * 4, stream);
  hipMemsetAsync(cnt, 0, (size_t)N * 4, stream);
  hist_kernel<<<(E + 255) / 256, 256, 0, stream>>>(dst, deg, E);
  scan_kernel<<<1, 1024, 0, stream>>>(deg, rowptr, N);
  scatter_kernel<<<(E + 255) / 256, 256, 0, stream>>>(dst, rowptr, cnt, eperm, E);

  int nWaves = (E + EPW - 1) / EPW;
  int eGrid = (nWaves + 3) / 4;  // 4 waves per 256-thread block

  for (int l = 0; l < 3; ++l) {
    int bi = 4 + 9 * l;
    const float* Wl = (const float*)d_in[bi + 0];
    const float* bl = (const float*)d_in[bi + 1];
    const float* Wr = (const float*)d_in[bi + 2];
    const float* br = (const float*)d_in[bi + 3];
    const float* We = (const float*)d_in[bi + 4];
    const float* att = (const float*)d_in[bi + 5];
    const float* bo = (const float*)d_in[bi + 6];
    const float* gg = (const float*)d_in[bi + 7];
    const float* be = (const float*)d_in[bi + 8];
    const float* Xin = (l == 0) ? x : ((l == 1) ? hA : hB);
    float* Xout = (l == 2) ? (float*)d_out : ((l == 0) ? hA : hB);

    int gemmGrid = (N + 63) / 64;
    node_gemm128<<<gemmGrid, 256, 0, stream>>>(Xin, Wl, bl, xl, N);
    node_gemm128<<<gemmGrid, 256, 0, stream>>>(Xin, Wr, br, xr, N);
    if (l < 2) {
      edge_scores<4><<<eGrid, 256, 0, stream>>>(xl, xr, ea, We, att, src, dst, sbuf, E);
      node_aggregate<4><<<(N + 3) / 4, 256, 0, stream>>>(xl, sbuf, rowptr, eperm, src,
                                                         bo, gg, be, Xout, N);
    } else {
      edge_scores<1><<<eGrid, 256, 0, stream>>>(xl, xr, ea, We, att, src, dst, sbuf, E);
      node_aggregate<1><<<(N + 3) / 4, 256, 0, stream>>>(xl, sbuf, rowptr, eperm, src,
                                                         bo, gg, be, Xout, N);
    }
  }
}

// Round 3
// 1408.507 us; speedup vs baseline: 1.2543x; 1.1682x over previous
//
#include <hip/hip_runtime.h>

// ---------------------------------------------------------------------------
// GATv2 3-layer GNN encoder. N=50000 nodes, E=800000 edges, dims 128.
// Phases: CSR build (once) -> per layer: [gemm xl, gemm xr,
// fused edge-score + segment-softmax + aggregate + bias + LN + ReLU].
// ---------------------------------------------------------------------------

__global__ __launch_bounds__(256) void hist_kernel(const int* __restrict__ dst,
                                                   int* __restrict__ deg, int nE) {
  int i = blockIdx.x * 256 + threadIdx.x;
  if (i < nE) atomicAdd(&deg[dst[i]], 1);
}

__global__ __launch_bounds__(1024) void scan_kernel(const int* __restrict__ deg,
                                                    int* __restrict__ rowptr, int n) {
  __shared__ int sdata[1024];
  int tid = threadIdx.x;
  if (tid == 0) rowptr[0] = 0;
  int carry = 0;
  for (int base = 0; base < n; base += 1024) {
    int i = base + tid;
    int v = (i < n) ? deg[i] : 0;
    sdata[tid] = v;
    __syncthreads();
    for (int ofs = 1; ofs < 1024; ofs <<= 1) {
      int t = (tid >= ofs) ? sdata[tid - ofs] : 0;
      __syncthreads();
      sdata[tid] += t;
      __syncthreads();
    }
    int inc = sdata[tid];
    int tot = sdata[1023];
    if (i < n) rowptr[i + 1] = carry + inc;
    carry += tot;
    __syncthreads();
  }
}

__global__ __launch_bounds__(256) void scatter_kernel(const int* __restrict__ dst,
                                                      const int* __restrict__ rowptr,
                                                      int* __restrict__ cnt,
                                                      int* __restrict__ eperm, int nE) {
  int i = blockIdx.x * 256 + threadIdx.x;
  if (i < nE) {
    int d = dst[i];
    int p = atomicAdd(&cnt[d], 1);
    eperm[rowptr[d] + p] = i;
  }
}

// Y[r][c] = sum_k X[r][k]*W[k][c] + bias[c].  X: nrows x 128, W: 128 x 128.
__global__ __launch_bounds__(256) void node_gemm128(const float* __restrict__ X,
                                                    const float* __restrict__ W,
                                                    const float* __restrict__ bias,
                                                    float* __restrict__ Y, int nrows) {
  __shared__ float Xs[64][36];
  __shared__ float Ws[32][128];
  int tid = threadIdx.x;
  int r0 = blockIdx.x * 64;
  int col = tid & 127;
  int rh = tid >> 7;
  float acc[32];
#pragma unroll
  for (int i = 0; i < 32; ++i) acc[i] = 0.f;

  for (int k0 = 0; k0 < 128; k0 += 32) {
    __syncthreads();
#pragma unroll
    for (int j = tid; j < 512; j += 256) {
      int r = j >> 3, kk = (j & 7) << 2;
      float4 v = make_float4(0.f, 0.f, 0.f, 0.f);
      if (r0 + r < nrows) v = *(const float4*)&X[(size_t)(r0 + r) * 128 + k0 + kk];
      *(float4*)&Xs[r][kk] = v;
    }
#pragma unroll
    for (int j = tid; j < 1024; j += 256) {
      int k = j >> 5, nn = (j & 31) << 2;
      float4 v = *(const float4*)&W[(size_t)(k0 + k) * 128 + nn];
      *(float4*)&Ws[k][nn] = v;
    }
    __syncthreads();
#pragma unroll
    for (int k4 = 0; k4 < 32; k4 += 4) {
      float w0 = Ws[k4][col], w1 = Ws[k4 + 1][col];
      float w2 = Ws[k4 + 2][col], w3 = Ws[k4 + 3][col];
#pragma unroll
      for (int r = 0; r < 32; ++r) {
        float4 xv = *(const float4*)&Xs[rh * 32 + r][k4];
        acc[r] += xv.x * w0 + xv.y * w1 + xv.z * w2 + xv.w * w3;
      }
    }
  }
  float b = bias[col];
#pragma unroll
  for (int r = 0; r < 32; ++r) {
    int row = r0 + rh * 32 + r;
    if (row < nrows) Y[(size_t)row * 128 + col] = acc[r] + b;
  }
}

// Fused per-node: for each in-edge e (CSR): score s[e,h] = att_h . lrelu(
// xl[src]+xr[n]+ea[e]@We), softmax over edges (max-free: scores bounded,
// clamped at 80), aggregate alpha*xl[src], +bias, LN, ReLU.
// One 64-lane wave per node. Lane owns dims {lane, lane+64}. We cols in regs.
// rb/re forced scalar -> whole edge loop runs on scalar loads (eperm/src/ea).
template <int H>
__global__ __launch_bounds__(256) void fused_gat(const float* __restrict__ xl,
                                                 const float* __restrict__ xr,
                                                 const float* __restrict__ ea,
                                                 const float* __restrict__ We,
                                                 const float* __restrict__ att,
                                                 const int* __restrict__ rowptr,
                                                 const int* __restrict__ eperm,
                                                 const int* __restrict__ src,
                                                 const float* __restrict__ bias,
                                                 const float* __restrict__ gam,
                                                 const float* __restrict__ bet,
                                                 float* __restrict__ out, int nN) {
  const int wid = threadIdx.x >> 6, lane = threadIdx.x & 63;
  const int n = blockIdx.x * 4 + wid;
  if (n >= nN) return;
  const int rb = __builtin_amdgcn_readfirstlane(rowptr[n]);
  const int re = __builtin_amdgcn_readfirstlane(rowptr[n + 1]);

  const float xr0 = xr[(size_t)n * 128 + lane];
  const float xr1 = xr[(size_t)n * 128 + lane + 64];
  float WcL[32], WcH[32];
#pragma unroll
  for (int k = 0; k < 32; ++k) {
    WcL[k] = We[k * 128 + lane];
    WcH[k] = We[k * 128 + lane + 64];
  }
  const float attL = att[lane], attH = att[lane + 64];

  float d0 = 0.f, d1 = 0.f, acc0 = 0.f, acc1 = 0.f;

  for (int j = rb; j < re; j += 2) {
    const bool has1 = (j + 1 < re);           // scalar predicate
    int e0 = eperm[j];                        // scalar loads (j uniform)
    int e1 = has1 ? eperm[j + 1] : e0;
    int s0 = src[e0];
    int s1 = src[e1];
    const float* x0 = xl + (size_t)s0 * 128;
    const float* x1 = xl + (size_t)s1 * 128;
    float a00 = x0[lane], a01 = x0[lane + 64];   // coalesced gathers, reused below
    float a10 = x1[lane], a11 = x1[lane + 64];
    const float* er0 = ea + (size_t)e0 * 32;
    const float* er1 = ea + (size_t)e1 * 32;

    float mL0 = a00 + xr0, mH0 = a01 + xr1;
    float mL1 = a10 + xr0, mH1 = a11 + xr1;
#pragma unroll
    for (int k = 0; k < 32; k += 4) {
      float4 q0 = *(const float4*)(er0 + k);  // uniform addr -> s_load_dwordx4
      float4 q1 = *(const float4*)(er1 + k);
      mL0 += q0.x * WcL[k] + q0.y * WcL[k + 1] + q0.z * WcL[k + 2] + q0.w * WcL[k + 3];
      mH0 += q0.x * WcH[k] + q0.y * WcH[k + 1] + q0.z * WcH[k + 2] + q0.w * WcH[k + 3];
      mL1 += q1.x * WcL[k] + q1.y * WcL[k + 1] + q1.z * WcL[k + 2] + q1.w * WcL[k + 3];
      mH1 += q1.x * WcH[k] + q1.y * WcH[k + 1] + q1.z * WcH[k + 2] + q1.w * WcH[k + 3];
    }
    // LeakyReLU(0.2) then att-dot partial
    float pL0 = fmaxf(mL0, 0.2f * mL0) * attL;
    float pH0 = fmaxf(mH0, 0.2f * mH0) * attH;
    float pL1 = fmaxf(mL1, 0.2f * mL1) * attL;
    float pH1 = fmaxf(mH1, 0.2f * mH1) * attH;

    if (H == 4) {
      // per-32-lane-group reduce: group g holds head g (low) / head 2+g (high)
#pragma unroll
      for (int o = 16; o >= 1; o >>= 1) {
        pL0 += __shfl_xor(pL0, o);
        pH0 += __shfl_xor(pH0, o);
        pL1 += __shfl_xor(pL1, o);
        pH1 += __shfl_xor(pH1, o);
      }
    } else {
      float p0 = pL0 + pH0, p1 = pL1 + pH1;
#pragma unroll
      for (int o = 32; o >= 1; o >>= 1) {
        p0 += __shfl_xor(p0, o);
        p1 += __shfl_xor(p1, o);
      }
      pL0 = pH0 = p0;
      pL1 = pH1 = p1;
    }

    float w00 = __expf(fminf(pL0, 80.f));
    float w01 = __expf(fminf(pH0, 80.f));
    d0 += w00;
    d1 += w01;
    acc0 += w00 * a00;
    acc1 += w01 * a01;
    if (has1) {
      float w10 = __expf(fminf(pL1, 80.f));
      float w11 = __expf(fminf(pH1, 80.f));
      d0 += w10;
      d1 += w11;
      acc0 += w10 * a10;
      acc1 += w11 * a11;
    }
  }

  const float rd0 = (d0 > 0.f) ? 1.f / d0 : 0.f;
  const float rd1 = (H == 4) ? ((d1 > 0.f) ? 1.f / d1 : 0.f) : rd0;
  float y0 = acc0 * rd0 + bias[lane];
  float y1 = acc1 * rd1 + bias[lane + 64];

  float sm = y0 + y1;
#pragma unroll
  for (int o = 32; o >= 1; o >>= 1) sm += __shfl_xor(sm, o);
  float mu = sm * (1.f / 128.f);
  float dd0 = y0 - mu, dd1 = y1 - mu;
  float vs = dd0 * dd0 + dd1 * dd1;
#pragma unroll
  for (int o = 32; o >= 1; o >>= 1) vs += __shfl_xor(vs, o);
  float rstd = rsqrtf(vs * (1.f / 128.f) + 1e-5f);
  float o0 = dd0 * rstd * gam[lane] + bet[lane];
  float o1 = dd1 * rstd * gam[lane + 64] + bet[lane + 64];
  out[(size_t)n * 128 + lane] = fmaxf(o0, 0.f);
  out[(size_t)n * 128 + lane + 64] = fmaxf(o1, 0.f);
}

extern "C" void kernel_launch(void* const* d_in, const int* in_sizes, int n_in,
                              void* d_out, int out_size, void* d_ws, size_t ws_size,
                              hipStream_t stream) {
  const float* x = (const float*)d_in[0];
  const float* ea = (const float*)d_in[1];
  const int* src = (const int*)d_in[2];
  const int* dst = (const int*)d_in[3];
  const int N = in_sizes[0] / 128;
  const int E = in_sizes[2];

  char* w = (char*)d_ws;
  auto alloc = [&](size_t bytes) {
    char* p = w;
    w += (bytes + 255) & ~(size_t)255;
    return p;
  };
  float* xl = (float*)alloc((size_t)N * 128 * 4);
  float* xr = (float*)alloc((size_t)N * 128 * 4);
  float* hA = (float*)alloc((size_t)N * 128 * 4);
  float* hB = (float*)alloc((size_t)N * 128 * 4);
  int* eperm = (int*)alloc((size_t)E * 4);
  int* rowptr = (int*)alloc((size_t)(N + 1) * 4);
  int* deg = (int*)alloc((size_t)N * 4);
  int* cnt = (int*)alloc((size_t)N * 4);

  // CSR by dst (src/dst constant across layers)
  hipMemsetAsync(deg, 0, (size_t)N * 4, stream);
  hipMemsetAsync(cnt, 0, (size_t)N * 4, stream);
  hist_kernel<<<(E + 255) / 256, 256, 0, stream>>>(dst, deg, E);
  scan_kernel<<<1, 1024, 0, stream>>>(deg, rowptr, N);
  scatter_kernel<<<(E + 255) / 256, 256, 0, stream>>>(dst, rowptr, cnt, eperm, E);

  for (int l = 0; l < 3; ++l) {
    int bi = 4 + 9 * l;
    const float* Wl = (const float*)d_in[bi + 0];
    const float* bl = (const float*)d_in[bi + 1];
    const float* Wr = (const float*)d_in[bi + 2];
    const float* br = (const float*)d_in[bi + 3];
    const float* We = (const float*)d_in[bi + 4];
    const float* att = (const float*)d_in[bi + 5];
    const float* bo = (const float*)d_in[bi + 6];
    const float* gg = (const float*)d_in[bi + 7];
    const float* be = (const float*)d_in[bi + 8];
    const float* Xin = (l == 0) ? x : ((l == 1) ? hA : hB);
    float* Xout = (l == 2) ? (float*)d_out : ((l == 0) ? hA : hB);

    int gemmGrid = (N + 63) / 64;
    node_gemm128<<<gemmGrid, 256, 0, stream>>>(Xin, Wl, bl, xl, N);
    node_gemm128<<<gemmGrid, 256, 0, stream>>>(Xin, Wr, br, xr, N);
    int nGrid = (N + 3) / 4;
    if (l < 2) {
      fused_gat<4><<<nGrid, 256, 0, stream>>>(xl, xr, ea, We, att, rowptr, eperm, src,
                                              bo, gg, be, Xout, N);
    } else {
      fused_gat<1><<<nGrid, 256, 0, stream>>>(xl, xr, ea, We, att, rowptr, eperm, src,
                                              bo, gg, be, Xout, N);
    }
  }
}